// Round 1
// baseline (360.150 us; speedup 1.0000x reference)
//
#include <hip/hip_runtime.h>

#define TAU_INV 100.0f
#define EPSB    1e-8f
#define NEGV    -1e9f

typedef float v4f __attribute__((ext_vector_type(4)));

// Fused kernel: wave 0 of every block recomputes the (deterministic) 64-lane
// iterative Gumbel top-K selection (~1k cycles), broadcasts sel via LDS, then
// all 256 threads grid-stride the patch gather (~4 float4/thread at 2560 blocks).
// Removes the separate select dispatch + workspace round-trip.
__global__ __launch_bounds__(256) void stk_fused(
    const float* __restrict__ logit,
    const float* __restrict__ bg,
    const float* __restrict__ gumbel,
    const v4f*   __restrict__ img,    // [4,256,256,256] as float4
    const v4f*   __restrict__ lab,    // [1,256,256,256] as float4
    v4f*         __restrict__ out,
    float*       __restrict__ ml_out, // 64 floats (output tail)
    int K, int nImg4, int nTot4)
{
    __shared__ int   s_idx[32];
    __shared__ float s_w[32];
    const int t = threadIdx.x;

    if (t < 64) {
        float lm = logf(fmaxf(1.0f - bg[t], EPSB));
        float ml = logit[t] + lm;
        if (blockIdx.x == 0) ml_out[t] = ml;   // masked_logit output, once
        float pv = ml + gumbel[t];             // perturbed, register-resident
        float mk = 0.0f;                       // accumulated -1e9 mask

        for (int k = 0; k < K; ++k) {
            float v  = pv + mk;
            // wave argmax (lower index wins ties, matching jnp.argmax)
            float bv = v;
            int   bi = t;
            #pragma unroll
            for (int off = 32; off >= 1; off >>= 1) {
                float vo = __shfl_xor(bv, off);
                int   io = __shfl_xor(bi, off);
                if (vo > bv || (vo == bv && io < bi)) { bv = vo; bi = io; }
            }
            // softmax denominator: sum_j exp((v_j - bv)/tau); masked lanes -> 0
            float e = __expf((v - bv) * TAU_INV);
            #pragma unroll
            for (int off = 32; off >= 1; off >>= 1)
                e += __shfl_xor(e, off);

            if (t == 0) { s_idx[k] = bi; s_w[k] = 1.0f / e; }
            if (t == bi) mk += NEGV;
        }
    }
    __syncthreads();

    const int stride = gridDim.x * blockDim.x;
    for (int tid = blockIdx.x * blockDim.x + t; tid < nTot4; tid += stride) {
        if (tid < nImg4) {
            // image region: [K,4,64,64,64] scaled by sel_w[k]
            int v   = tid;
            int dp4 = v & 15;
            int wp  = (v >> 4)  & 63;
            int hp  = (v >> 10) & 63;
            int c   = (v >> 16) & 3;
            int k   = v >> 18;
            int n   = s_idx[k];
            int hn  = n >> 4, wn = (n >> 2) & 3, dn = n & 3;
            int src = c * 4194304 + (hn * 64 + hp) * 16384 + (wn * 64 + wp) * 64 + dn * 16 + dp4;
            v4f d = __builtin_nontemporal_load(&img[src]);
            d *= s_w[k];
            __builtin_nontemporal_store(d, &out[tid]);
        } else {
            // label region: [K,1,64,64,64] unscaled
            int u   = tid - nImg4;
            int dp4 = u & 15;
            int wp  = (u >> 4)  & 63;
            int hp  = (u >> 10) & 63;
            int k   = u >> 16;
            int n   = s_idx[k];
            int hn  = n >> 4, wn = (n >> 2) & 3, dn = n & 3;
            int src = (hn * 64 + hp) * 16384 + (wn * 64 + wp) * 64 + dn * 16 + dp4;
            v4f d = __builtin_nontemporal_load(&lab[src]);
            __builtin_nontemporal_store(d, &out[tid]);
        }
    }
}

extern "C" void kernel_launch(void* const* d_in, const int* in_sizes, int n_in,
                              void* d_out, int out_size, void* d_ws, size_t ws_size,
                              hipStream_t stream) {
    const float* image  = (const float*)d_in[0];  // [1,4,256,256,256]
    const float* label  = (const float*)d_in[1];  // [1,1,256,256,256]
    const float* logit  = (const float*)d_in[2];  // [1,1,4,4,4]
    const float* bg     = (const float*)d_in[3];  // [1,1,4,4,4]
    const float* gumbel = (const float*)d_in[4];  // [1,64]
    // out_size (floats) = K*(4+1)*64^3 + 64
    int K = (out_size - 64) / (5 * 64 * 64 * 64);

    float* out    = (float*)d_out;
    float* ml_out = out + (size_t)K * 1310720;    // K*(4+1)*262144

    int nImg4 = K * 4 * 65536;
    int nTot4 = nImg4 + K * 65536;

    // ~4 float4 per thread; keeps per-block selection redundancy cheap
    int blocks = (nTot4 + 1023) / 1024;
    if (blocks < 1) blocks = 1;
    stk_fused<<<blocks, 256, 0, stream>>>(logit, bg, gumbel,
                                          (const v4f*)image, (const v4f*)label,
                                          (v4f*)out, ml_out, K, nImg4, nTot4);
}